// Round 5
// baseline (29144.061 us; speedup 1.0000x reference)
//
#include <hip/hip_runtime.h>

#define SEQ  4096
#define NB   64
#define NI   64
#define NH   256

typedef short  bf16x8 __attribute__((ext_vector_type(8)));
typedef short  bf16x2 __attribute__((ext_vector_type(2)));
typedef float  f32x4  __attribute__((ext_vector_type(4)));

__device__ __forceinline__ unsigned short f2bf(float f) {
    union { float f; unsigned u; } v; v.f = f;
    return (unsigned short)((v.u + 0x7fffu + ((v.u >> 16) & 1u)) >> 16);
}
__device__ __forceinline__ float fast_rcp(float x) { return __builtin_amdgcn_rcpf(x); }
__device__ __forceinline__ float sigm(float x) { return fast_rcp(1.f + __expf(-x)); }
__device__ __forceinline__ float tanh_(float x) {
    x = fminf(15.f, fmaxf(-15.f, x));
    float e = __expf(2.f * x);
    return (e - 1.f) * fast_rcp(e + 1.f);
}
__device__ __forceinline__ f32x4 mfma16(bf16x8 a, bf16x8 b, f32x4 c) {
    return __builtin_amdgcn_mfma_f32_16x16x32_bf16(a, b, c, 0, 0, 0);
}
__device__ __forceinline__ bf16x8 ldfrag(const float* p) {
    float4 a = *(const float4*)p;
    float4 b = *(const float4*)(p + 4);
    bf16x8 r;
    r[0] = (short)f2bf(a.x); r[1] = (short)f2bf(a.y);
    r[2] = (short)f2bf(a.z); r[3] = (short)f2bf(a.w);
    r[4] = (short)f2bf(b.x); r[5] = (short)f2bf(b.y);
    r[6] = (short)f2bf(b.z); r[7] = (short)f2bf(b.w);
    return r;
}

// Single fused kernel. grid 4 x 512 threads (8 waves).
// Block bc: batch rows bc*16..+15. Wave wv: hidden cols [wv*32, wv*32+32)
// = j-blocks jb0 (cols +0..15) and jb1 (cols +16..31), all 3 gates.
// ALL weights register-resident: W_hh 192 regs + W_ih 48 regs (AGPR),
// fc frags 32 regs (VGPR). LDS only stages h (16 KB dbuf) + x (4 KB dbuf)
// + out ring (4 KB). x-projection is fused (+12 MFMA/wave/step).
// A-frag addr (row b, k): (k>>5)*512 + (((k>>3)&3)*16 + b)*8 + (k&7) shorts.
// MFMA 16x16x32 C/D: col = lane&15, row = (lane>>4)*4 + reg.
__global__ __launch_bounds__(512, 2) void gru_all(
        const float* __restrict__ x,
        const float* __restrict__ w_ih,
        const float* __restrict__ w_hh,
        const float* __restrict__ b_ih,
        const float* __restrict__ b_hh,
        const float* __restrict__ fc_w,
        const float* __restrict__ fc_b,
        float* __restrict__ out)
{
    __shared__ short abuf[8192];     // h staging, 2 x 8 chunks x 512 shorts
    __shared__ short xstg[2048];     // x staging, 2 x 2 chunks x 512 shorts
    __shared__ float oring[1024];    // out ring, 2 banks x 32 steps x 16 batch

    const int tid = threadIdx.x, wv = tid >> 6, lane = tid & 63;
    const int nn = lane & 15, q = lane >> 4;
    const int bbase = blockIdx.x * 16;

    // ---- one-time: ALL weights into registers ----
    bf16x8 whh[6][8];                // [jb*3 + gate][K-chunk], r/z/n
    bf16x8 wih[6][2];
    float br[2], bz[2], bxn[2], bhn[2];
    #pragma unroll
    for (int jb = 0; jb < 2; ++jb) {
        const int col = wv * 32 + jb * 16 + nn;
        #pragma unroll
        for (int g = 0; g < 3; ++g) {
            const int row = g * NH + col;
            #pragma unroll
            for (int c = 0; c < 8; ++c)
                whh[jb * 3 + g][c] = ldfrag(w_hh + row * NH + c * 32 + q * 8);
            #pragma unroll
            for (int c = 0; c < 2; ++c)
                wih[jb * 3 + g][c] = ldfrag(w_ih + row * NI + c * 32 + q * 8);
        }
        br[jb]  = b_ih[col] + b_hh[col];
        bz[jb]  = b_ih[NH + col] + b_hh[NH + col];
        bxn[jb] = b_ih[2 * NH + col];
        bhn[jb] = b_hh[2 * NH + col];
    }
    bf16x8 fcf[8];                   // fc B-frags: col nn==0 = fc_w, else 0
    #pragma unroll
    for (int c = 0; c < 8; ++c) {
        bf16x8 f = 0;
        if (nn == 0) f = ldfrag(fc_w + c * 32 + q * 8);
        fcf[c] = f;
    }
    const float fcb = fc_b[0];

    // ---- init: h_0 = 0 (buffer 0), stage x_0 ----
    ((int4*)abuf)[tid] = make_int4(0, 0, 0, 0);
    {
        const int f = 2 * tid, b = f >> 6, k = f & 63;
        float2 v = *(const float2*)(x + bbase * NI + f);
        bf16x2 s; s[0] = (short)f2bf(v.x); s[1] = (short)f2bf(v.y);
        *(bf16x2*)(xstg + (k >> 5) * 512 + (((k >> 3) & 3) * 16 + b) * 8 + (k & 7)) = s;
    }
    f32x4 hp0 = {0.f, 0.f, 0.f, 0.f}, hp1 = {0.f, 0.f, 0.f, 0.f};
    const float* xp = x + (size_t)NB * NI + bbase * NI + 2 * tid;  // x_{t+1}

    const int j0 = wv * 32 + nn;
    const int koff0 = (j0 >> 5) * 512 + ((j0 >> 3) & 3) * 128 + (j0 & 7) + q * 32;
    const int koff1 = koff0 + 256;   // cols +16: ((j>>3)&3) bumps by 2
    __syncthreads();

    for (int t = 0; t < SEQ; ++t) {
        const int cur = t & 1, nxt = cur ^ 1;
        const bool hn = (t + 1 < SEQ);
        float2 xv = make_float2(0.f, 0.f);
        if (hn) xv = *(const float2*)xp;
        xp += NB * NI;

        // out flush once per 32 steps (slots all >=1 barrier old)
        if ((t & 31) == 1 && t >= 33) {
            const int s0 = t - 33;
            out[(size_t)(s0 + (tid >> 4)) * NB + bbase + (tid & 15)] =
                oring[(((s0 >> 5) & 1) << 9) + (tid >> 4) * 16 + (tid & 15)];
        }

        // accumulators pre-loaded with folded biases
        f32x4 ar0 = {br[0],br[0],br[0],br[0]},  ar1 = {br[1],br[1],br[1],br[1]};
        f32x4 az0 = {bz[0],bz[0],bz[0],bz[0]},  az1 = {bz[1],bz[1],bz[1],bz[1]};
        f32x4 an0 = {bhn[0],bhn[0],bhn[0],bhn[0]}, an1 = {bhn[1],bhn[1],bhn[1],bhn[1]};
        f32x4 ax0 = {bxn[0],bxn[0],bxn[0],bxn[0]}, ax1 = {bxn[1],bxn[1],bxn[1],bxn[1]};
        f32x4 afc = {0.f, 0.f, 0.f, 0.f};
        const bool isfc = (t > 0) && (wv == (t & 7));

        const short* ab = abuf + cur * 4096;
        #pragma unroll
        for (int c = 0; c < 8; ++c) {
            bf16x8 av = *(const bf16x8*)(ab + c * 512 + lane * 8);
            ar0 = mfma16(av, whh[0][c], ar0);
            az0 = mfma16(av, whh[1][c], az0);
            an0 = mfma16(av, whh[2][c], an0);
            ar1 = mfma16(av, whh[3][c], ar1);
            az1 = mfma16(av, whh[4][c], az1);
            an1 = mfma16(av, whh[5][c], an1);
            if (isfc) afc = mfma16(av, fcf[c], afc);   // FC(h_{t-1}) rides along
        }
        const short* xb = xstg + cur * 1024;
        #pragma unroll
        for (int c = 0; c < 2; ++c) {
            bf16x8 axv = *(const bf16x8*)(xb + c * 512 + lane * 8);
            ar0 = mfma16(axv, wih[0][c], ar0);
            az0 = mfma16(axv, wih[1][c], az0);
            ax0 = mfma16(axv, wih[2][c], ax0);
            ar1 = mfma16(axv, wih[3][c], ar1);
            az1 = mfma16(axv, wih[4][c], az1);
            ax1 = mfma16(axv, wih[5][c], ax1);
        }

        if (isfc && nn == 0) {       // write out[t-1] into the ring
            const int s = t - 1;
            f32x4 v;
            #pragma unroll
            for (int m = 0; m < 4; ++m) v[m] = afc[m] + fcb;
            *(f32x4*)(oring + (((s >> 5) & 1) << 9) + ((s & 31) << 4) + q * 4) = v;
        }

        short* hw = abuf + nxt * 4096;
        #pragma unroll
        for (int m = 0; m < 4; ++m) {
            float r_ = sigm(ar0[m]);
            float z_ = sigm(az0[m]);
            float n_ = tanh_(fmaf(r_, an0[m], ax0[m]));
            float h_ = n_ + z_ * (hp0[m] - n_);
            hp0[m] = h_;
            hw[koff0 + m * 8] = (short)f2bf(h_);
        }
        #pragma unroll
        for (int m = 0; m < 4; ++m) {
            float r_ = sigm(ar1[m]);
            float z_ = sigm(az1[m]);
            float n_ = tanh_(fmaf(r_, an1[m], ax1[m]));
            float h_ = n_ + z_ * (hp1[m] - n_);
            hp1[m] = h_;
            hw[koff1 + m * 8] = (short)f2bf(h_);
        }

        if (hn) {                    // stage x_{t+1}
            const int f = 2 * tid, b = f >> 6, k = f & 63;
            bf16x2 s; s[0] = (short)f2bf(xv.x); s[1] = (short)f2bf(xv.y);
            *(bf16x2*)(xstg + nxt * 1024 +
                       (k >> 5) * 512 + (((k >> 3) & 3) * 16 + b) * 8 + (k & 7)) = s;
        }
        __syncthreads();             // single per-step barrier (all LDS dbuf'd)
    }

    // ---- tail: FC for s = SEQ-1 (final h is in buffer 0), flush last 32 ----
    if (wv == 0) {
        f32x4 afc = {0.f, 0.f, 0.f, 0.f};
        #pragma unroll
        for (int c = 0; c < 8; ++c)
            afc = mfma16(*(const bf16x8*)(abuf + c * 512 + lane * 8), fcf[c], afc);
        if (nn == 0) {
            const int s = SEQ - 1;
            #pragma unroll
            for (int m = 0; m < 4; ++m)
                oring[(((s >> 5) & 1) << 9) + ((s & 31) << 4) + q * 4 + m] = afc[m] + fcb;
        }
    }
    __syncthreads();
    {
        const int s0 = SEQ - 32;
        out[(size_t)(s0 + (tid >> 4)) * NB + bbase + (tid & 15)] =
            oring[(((s0 >> 5) & 1) << 9) + (tid >> 4) * 16 + (tid & 15)];
    }
}

extern "C" void kernel_launch(void* const* d_in, const int* in_sizes, int n_in,
                              void* d_out, int out_size, void* d_ws, size_t ws_size,
                              hipStream_t stream) {
    (void)in_sizes; (void)n_in; (void)d_ws; (void)ws_size; (void)out_size;
    gru_all<<<dim3(4), dim3(512), 0, stream>>>(
        (const float*)d_in[0], (const float*)d_in[1], (const float*)d_in[2],
        (const float*)d_in[3], (const float*)d_in[4], (const float*)d_in[5],
        (const float*)d_in[6], (float*)d_out);
}

// Round 6
// 17054.800 us; speedup vs baseline: 1.7088x; 1.7088x over previous
//
#include <hip/hip_runtime.h>

#define SEQ  4096
#define NB   64
#define NI   64
#define NH   256

typedef short  bf16x8 __attribute__((ext_vector_type(8)));
typedef short  bf16x2 __attribute__((ext_vector_type(2)));
typedef float  f32x4  __attribute__((ext_vector_type(4)));

__device__ __forceinline__ unsigned short f2bf(float f) {
    union { float f; unsigned u; } v; v.f = f;
    return (unsigned short)((v.u + 0x7fffu + ((v.u >> 16) & 1u)) >> 16);
}
__device__ __forceinline__ float fast_rcp(float x) { return __builtin_amdgcn_rcpf(x); }
__device__ __forceinline__ float sigm(float x) { return fast_rcp(1.f + __expf(-x)); }
__device__ __forceinline__ float tanh_(float x) {
    x = fminf(15.f, fmaxf(-15.f, x));
    float e = __expf(2.f * x);
    return (e - 1.f) * fast_rcp(e + 1.f);
}
__device__ __forceinline__ f32x4 mfma16(bf16x8 a, bf16x8 b, f32x4 c) {
    return __builtin_amdgcn_mfma_f32_16x16x32_bf16(a, b, c, 0, 0, 0);
}
__device__ __forceinline__ bf16x8 ldfrag(const float* p) {
    float4 a = *(const float4*)p;
    float4 b = *(const float4*)(p + 4);
    bf16x8 r;
    r[0] = (short)f2bf(a.x); r[1] = (short)f2bf(a.y);
    r[2] = (short)f2bf(a.z); r[3] = (short)f2bf(a.w);
    r[4] = (short)f2bf(b.x); r[5] = (short)f2bf(b.y);
    r[6] = (short)f2bf(b.z); r[7] = (short)f2bf(b.w);
    return r;
}

// Single fused kernel. grid 4 x 512 threads (8 waves), 2 waves/SIMD
// -> 256 unified regs/wave. Block: batch rows bc*16..+15. Wave wv: hidden
// cols [wv*32, wv*32+32) = j-blocks jb0/jb1, all 3 gates.
// Register budget (the r2/r5 lesson: keep total <= ~250):
//   AGPR: r/z augmented [W_hh|W_ih] (K=320, 10 chunks) 40 frags = 160 regs
//         + n-gate W_ih 4 frags = 16  -> 176
//   VGPR: 8 acc (32) + hp (8) + biases (8) + temps/addr (~35)  -> ~80
//   n-gate W_hh -> LDS (the 64 regs that sank round 5).
// FC is a separate 1-wave pass after the MFMA loop (keeps peak pressure low).
// LDS: wlds 128K | abuf aug dbuf 20K | fcwl 8K | oring 2K = 161792 B.
// A-frag addr (row b, k): (k>>5)*512 + (((k>>3)&3)*16 + b)*8 + (k&7) shorts.
// MFMA 16x16x32 C/D: col = lane&15, row = (lane>>4)*4 + reg.
__global__ __launch_bounds__(512, 2) void gru_fused(
        const float* __restrict__ x,
        const float* __restrict__ w_ih,
        const float* __restrict__ w_hh,
        const float* __restrict__ b_ih,
        const float* __restrict__ b_hh,
        const float* __restrict__ fc_w,
        const float* __restrict__ fc_b,
        float* __restrict__ out)
{
    __shared__ short wlds[65536];    // n-gate W_hh: 16 jb-slots x 8 chunks x 512
    __shared__ short abuf[10240];    // [h(8)|x(2)] aug dbuf: 2 x 10 chunks x 512
    __shared__ short fcwl[4096];     // fc B-frags (col nn==0 live), 8 x 512
    __shared__ float oring[512];     // out ring: 2 banks x 16 steps x 16 batch

    const int tid = threadIdx.x, wv = tid >> 6, lane = tid & 63;
    const int nn = lane & 15, q = lane >> 4;
    const int bbase = blockIdx.x * 16;

    // ---- one-time weight staging ----
    bf16x8 wrz[4][10];               // [jb*2+g][chunk], g: 0=r 1=z, aug K=320
    float br[2], bz[2], bxn[2], bhn[2];
    #pragma unroll
    for (int jb = 0; jb < 2; ++jb) {
        const int col = wv * 32 + jb * 16 + nn;
        #pragma unroll
        for (int g = 0; g < 2; ++g) {
            const int row = g * NH + col;
            #pragma unroll
            for (int c = 0; c < 8; ++c)
                wrz[jb * 2 + g][c] = ldfrag(w_hh + row * NH + c * 32 + q * 8);
            #pragma unroll
            for (int c = 8; c < 10; ++c)
                wrz[jb * 2 + g][c] = ldfrag(w_ih + row * NI + (c - 8) * 32 + q * 8);
        }
        br[jb]  = b_ih[col] + b_hh[col];
        bz[jb]  = b_ih[NH + col] + b_hh[NH + col];
        bxn[jb] = b_ih[2 * NH + col];
        bhn[jb] = b_hh[2 * NH + col];
    }
    bf16x8 wnx[2][2];                // n-gate W_ih (AGPR)
    #pragma unroll
    for (int jb = 0; jb < 2; ++jb)
        #pragma unroll
        for (int c = 0; c < 2; ++c)
            wnx[jb][c] = ldfrag(w_ih + (2 * NH + wv * 32 + jb * 16 + nn) * NI
                                + c * 32 + q * 8);
    #pragma unroll
    for (int jb = 0; jb < 2; ++jb)   // n-gate W_hh -> LDS
        #pragma unroll
        for (int c = 0; c < 8; ++c) {
            bf16x8 f = ldfrag(w_hh + (2 * NH + wv * 32 + jb * 16 + nn) * NH
                              + c * 32 + q * 8);
            *(bf16x8*)(wlds + ((wv * 2 + jb) * 8 + c) * 512 + lane * 8) = f;
        }
    {                                // fc frags: wave wv stages chunk wv
        bf16x8 f = 0;
        if (nn == 0) f = ldfrag(fc_w + wv * 32 + q * 8);
        *(bf16x8*)(fcwl + wv * 512 + lane * 8) = f;
    }
    const float fcb = fc_b[0];

    // ---- init: H_0 = 0 (buf 0 chunks 0-7), stage x_0 (chunks 8,9) ----
    ((int4*)abuf)[tid] = make_int4(0, 0, 0, 0);
    {
        const int f = 2 * tid, b = f >> 6, k = f & 63;
        float2 v = *(const float2*)(x + bbase * NI + f);
        bf16x2 s; s[0] = (short)f2bf(v.x); s[1] = (short)f2bf(v.y);
        *(bf16x2*)(abuf + (8 + (k >> 5)) * 512 +
                   (((k >> 3) & 3) * 16 + b) * 8 + (k & 7)) = s;
    }
    f32x4 hp0 = {0.f, 0.f, 0.f, 0.f}, hp1 = {0.f, 0.f, 0.f, 0.f};
    const float* xp = x + (size_t)(NB + bbase) * NI + 2 * tid;   // x_{t+1}

    const int j0 = wv * 32 + nn;
    const int koff0 = (j0 >> 5) * 512 + ((j0 >> 3) & 3) * 128 + (j0 & 7) + q * 32;
    const int koff1 = koff0 + 256;
    __syncthreads();

    for (int t = 0; t < SEQ; ++t) {
        const int cur = t & 1, nxt = cur ^ 1;
        const bool hn = (t + 1 < SEQ);
        float2 xv = make_float2(0.f, 0.f);
        if (hn) xv = *(const float2*)xp;
        xp += NB * NI;

        // out flush once per 16 steps; slots >= 15 barriers old
        if ((t & 15) == 1 && t >= 17 && tid < 256) {
            const int s0 = t - 17;
            out[(size_t)(s0 + (tid >> 4)) * NB + bbase + (tid & 15)] =
                oring[(((s0 >> 4) & 1) << 8) + (tid >> 4) * 16 + (tid & 15)];
        }

        f32x4 ar0 = {br[0],br[0],br[0],br[0]},   ar1 = {br[1],br[1],br[1],br[1]};
        f32x4 az0 = {bz[0],bz[0],bz[0],bz[0]},   az1 = {bz[1],bz[1],bz[1],bz[1]};
        f32x4 an0 = {bhn[0],bhn[0],bhn[0],bhn[0]}, an1 = {bhn[1],bhn[1],bhn[1],bhn[1]};
        f32x4 ax0 = {bxn[0],bxn[0],bxn[0],bxn[0]}, ax1 = {bxn[1],bxn[1],bxn[1],bxn[1]};

        const short* ab = abuf + cur * 5120;
        #pragma unroll
        for (int c = 0; c < 8; ++c) {           // h part (chunks 0-7)
            bf16x8 av = *(const bf16x8*)(ab + c * 512 + lane * 8);
            ar0 = mfma16(av, wrz[0][c], ar0);
            az0 = mfma16(av, wrz[1][c], az0);
            ar1 = mfma16(av, wrz[2][c], ar1);
            az1 = mfma16(av, wrz[3][c], az1);
            bf16x8 wn0 = *(const bf16x8*)(wlds + ((wv * 2) * 8 + c) * 512 + lane * 8);
            an0 = mfma16(av, wn0, an0);
            bf16x8 wn1 = *(const bf16x8*)(wlds + ((wv * 2 + 1) * 8 + c) * 512 + lane * 8);
            an1 = mfma16(av, wn1, an1);
        }
        #pragma unroll
        for (int c = 8; c < 10; ++c) {          // x part (chunks 8,9)
            bf16x8 av = *(const bf16x8*)(ab + c * 512 + lane * 8);
            ar0 = mfma16(av, wrz[0][c], ar0);
            az0 = mfma16(av, wrz[1][c], az0);
            ar1 = mfma16(av, wrz[2][c], ar1);
            az1 = mfma16(av, wrz[3][c], az1);
            ax0 = mfma16(av, wnx[0][c - 8], ax0);
            ax1 = mfma16(av, wnx[1][c - 8], ax1);
        }

        // FC(H_t) -> out[t-1]: separate short pass on one rotating wave,
        // kept out of the main loop to lower peak register pressure.
        if (t > 0 && wv == (t & 7)) {
            f32x4 afc = {0.f, 0.f, 0.f, 0.f};
            #pragma unroll
            for (int c = 0; c < 8; ++c)
                afc = mfma16(*(const bf16x8*)(ab + c * 512 + lane * 8),
                             *(const bf16x8*)(fcwl + c * 512 + lane * 8), afc);
            if (nn == 0) {
                const int s = t - 1;
                f32x4 v;
                #pragma unroll
                for (int m = 0; m < 4; ++m) v[m] = afc[m] + fcb;
                *(f32x4*)(oring + (((s >> 4) & 1) << 8) + ((s & 15) << 4) + q * 4) = v;
            }
        }

        short* hw = abuf + nxt * 5120;
        #pragma unroll
        for (int m = 0; m < 4; ++m) {
            float r_ = sigm(ar0[m]);
            float z_ = sigm(az0[m]);
            float n_ = tanh_(fmaf(r_, an0[m], ax0[m]));
            float h_ = n_ + z_ * (hp0[m] - n_);
            hp0[m] = h_;
            hw[koff0 + m * 8] = (short)f2bf(h_);
        }
        #pragma unroll
        for (int m = 0; m < 4; ++m) {
            float r_ = sigm(ar1[m]);
            float z_ = sigm(az1[m]);
            float n_ = tanh_(fmaf(r_, an1[m], ax1[m]));
            float h_ = n_ + z_ * (hp1[m] - n_);
            hp1[m] = h_;
            hw[koff1 + m * 8] = (short)f2bf(h_);
        }

        if (hn) {                               // stage x_{t+1} into buf nxt
            const int f = 2 * tid, b = f >> 6, k = f & 63;
            bf16x2 s; s[0] = (short)f2bf(xv.x); s[1] = (short)f2bf(xv.y);
            *(bf16x2*)(abuf + nxt * 5120 + (8 + (k >> 5)) * 512 +
                       (((k >> 3) & 3) * 16 + b) * 8 + (k & 7)) = s;
        }
        __syncthreads();                        // single per-step barrier
    }

    // ---- tail: FC(H_SEQ) -> out[SEQ-1], flush last 16 ----
    if (wv == 0) {
        f32x4 afc = {0.f, 0.f, 0.f, 0.f};
        #pragma unroll
        for (int c = 0; c < 8; ++c)
            afc = mfma16(*(const bf16x8*)(abuf + c * 512 + lane * 8),
                         *(const bf16x8*)(fcwl + c * 512 + lane * 8), afc);
        if (nn == 0) {
            const int s = SEQ - 1;
            #pragma unroll
            for (int m = 0; m < 4; ++m)
                oring[(((s >> 4) & 1) << 8) + ((s & 15) << 4) + q * 4 + m] = afc[m] + fcb;
        }
    }
    __syncthreads();
    if (tid < 256) {
        const int s0 = SEQ - 16;
        out[(size_t)(s0 + (tid >> 4)) * NB + bbase + (tid & 15)] =
            oring[(((s0 >> 4) & 1) << 8) + (tid >> 4) * 16 + (tid & 15)];
    }
}

extern "C" void kernel_launch(void* const* d_in, const int* in_sizes, int n_in,
                              void* d_out, int out_size, void* d_ws, size_t ws_size,
                              hipStream_t stream) {
    (void)in_sizes; (void)n_in; (void)d_ws; (void)ws_size; (void)out_size;
    gru_fused<<<dim3(4), dim3(512), 0, stream>>>(
        (const float*)d_in[0], (const float*)d_in[1], (const float*)d_in[2],
        (const float*)d_in[3], (const float*)d_in[4], (const float*)d_in[5],
        (const float*)d_in[6], (float*)d_out);
}

// Round 7
// 15799.535 us; speedup vs baseline: 1.8446x; 1.0794x over previous
//
#include <hip/hip_runtime.h>
#include <hip/hip_cooperative_groups.h>

namespace cg = cooperative_groups;

#define SEQ  4096
#define NB   64
#define NI   64
#define NH   256

typedef short  bf16x8 __attribute__((ext_vector_type(8)));
typedef short  bf16x4 __attribute__((ext_vector_type(4)));
typedef float  f32x4  __attribute__((ext_vector_type(4)));

__device__ __forceinline__ unsigned short f2bf(float f) {
    union { float f; unsigned u; } v; v.f = f;
    return (unsigned short)((v.u + 0x7fffu + ((v.u >> 16) & 1u)) >> 16);
}
__device__ __forceinline__ float bflo(int p) {
    union { int i; float f; } u; u.i = p << 16; return u.f;
}
__device__ __forceinline__ float bfhi(int p) {
    union { int i; float f; } u; u.i = p & 0xffff0000; return u.f;
}
__device__ __forceinline__ float fast_rcp(float x) { return __builtin_amdgcn_rcpf(x); }
__device__ __forceinline__ float sigm(float x) { return fast_rcp(1.f + __expf(-x)); }
__device__ __forceinline__ float tanh_(float x) {
    x = fminf(15.f, fmaxf(-15.f, x));
    float e = __expf(2.f * x);
    return (e - 1.f) * fast_rcp(e + 1.f);
}
__device__ __forceinline__ f32x4 mfma16(bf16x8 a, bf16x8 b, f32x4 c) {
    return __builtin_amdgcn_mfma_f32_16x16x32_bf16(a, b, c, 0, 0, 0);
}
__device__ __forceinline__ bf16x8 ldfrag(const float* p) {
    float4 a = *(const float4*)p;
    float4 b = *(const float4*)(p + 4);
    bf16x8 r;
    r[0] = (short)f2bf(a.x); r[1] = (short)f2bf(a.y);
    r[2] = (short)f2bf(a.z); r[3] = (short)f2bf(a.w);
    r[4] = (short)f2bf(b.x); r[5] = (short)f2bf(b.y);
    r[6] = (short)f2bf(b.z); r[7] = (short)f2bf(b.w);
    return r;
}

// Producer tile: xg[g*plane + ((rt*16 + jb)*64 + lane)*4 + m], jb = wv.
// r/z get b_ih + b_hh folded; n gets b_ih only (consumer adds bhn inside r*()).
__device__ __forceinline__ void prod_tile(
        const float* __restrict__ x, short* __restrict__ dst, size_t plane,
        int t0, int rt, int wv, int lane, int nn, int q,
        const bf16x8 wp[3][2], const float bb[3])
{
    const float* xr = x + ((size_t)t0 * NB + (size_t)rt * 16 + nn) * NI + q * 8;
    bf16x8 a0 = ldfrag(xr);
    bf16x8 a1 = ldfrag(xr + 32);
    #pragma unroll
    for (int g = 0; g < 3; ++g) {
        f32x4 acc = {0.f, 0.f, 0.f, 0.f};
        acc = mfma16(a0, wp[g][0], acc);
        acc = mfma16(a1, wp[g][1], acc);
        bf16x4 v;
        #pragma unroll
        for (int m = 0; m < 4; ++m) v[m] = (short)f2bf(acc[m] + bb[g]);
        *(bf16x4*)(dst + (size_t)g * plane +
                   (((size_t)rt * 16 + wv) * 64 + lane) * 4) = v;
    }
}

// Cooperative single dispatch. 256 blocks x 1024 threads, 1 block/CU (LDS-
// limited). Blocks 0-3: persistent consumers = round-4's proven gru_rec
// (wave wv owns j-block wv; r/z W_hh in AGPR (64), n-gate in LDS; FC rides
// as an extra MFMA on a rotating wave; out via LDS ring). Blocks 4-255:
// producers — compute xg chunk c+1 (x·W_ih^T + bias, bf16) into a double-
// buffered d_ws region while consumers chew chunk c. grid.sync() per chunk
// gives cross-XCD ordering. Register law (r2/r5/r6): stay at the proven
// 64 VGPR + 64 AGPR point of the 16-wave config.
__global__ __launch_bounds__(1024, 4) void gru_coop(
        const float* __restrict__ x,
        const float* __restrict__ w_ih,
        const float* __restrict__ w_hh,
        const float* __restrict__ b_ih,
        const float* __restrict__ b_hh,
        const float* __restrict__ fc_w,
        const float* __restrict__ fc_b,
        float* __restrict__ out,
        short* __restrict__ xg,
        int spc, int nc)
{
    __shared__ short wlds[65536];    // n-gate W_hh: 16 jb x 8 chunks x 512
    __shared__ short abuf[8192];     // h staging, 2 x 8 chunks x 512
    __shared__ short fcwl[4096];     // fc B-frags (col nn==0 live), 8 x 512
    __shared__ float oring[1024];    // out ring, 2 x 32 steps x 16 batch

    const int tid = threadIdx.x, wv = tid >> 6, lane = tid & 63;
    const int nn = lane & 15, q = lane >> 4;
    const int bid = blockIdx.x;
    const bool cons = (bid < 4);
    const size_t plane = (size_t)spc * 16384;   // shorts per gate plane
    const size_t bufsz = 3 * plane;             // shorts per chunk buffer

    // ---- producer weights (all blocks produce chunk 0) ----
    bf16x8 wp[3][2];
    float bb[3];
    #pragma unroll
    for (int g = 0; g < 3; ++g) {
        const int row = g * NH + wv * 16 + nn;
        wp[g][0] = ldfrag(w_ih + row * NI + q * 8);
        wp[g][1] = ldfrag(w_ih + row * NI + 32 + q * 8);
        bb[g] = b_ih[row] + (g < 2 ? b_hh[row] : 0.f);
    }

    // ---- consumer one-time staging ----
    bf16x8 wr[8], wz[8];
    float bhn = 0.f, fcb = 0.f;
    int koff = 0;
    if (cons) {
        #pragma unroll
        for (int c = 0; c < 8; ++c)
            wr[c] = ldfrag(w_hh + (wv * 16 + nn) * NH + c * 32 + q * 8);
        #pragma unroll
        for (int c = 0; c < 8; ++c)
            wz[c] = ldfrag(w_hh + (NH + wv * 16 + nn) * NH + c * 32 + q * 8);
        #pragma unroll
        for (int c = 0; c < 8; ++c) {
            bf16x8 f = ldfrag(w_hh + (2 * NH + wv * 16 + nn) * NH + c * 32 + q * 8);
            *(bf16x8*)(wlds + (wv * 8 + c) * 512 + lane * 8) = f;
        }
        if (wv < 8) {
            bf16x8 f = 0;
            if (nn == 0) f = ldfrag(fc_w + wv * 32 + q * 8);
            *(bf16x8*)(fcwl + wv * 512 + lane * 8) = f;
        }
        bhn = b_hh[2 * NH + wv * 16 + nn];
        fcb = fc_b[0];
        ((int4*)abuf)[tid] = make_int4(0, 0, 0, 0);   // h_0 = 0 (both bufs)
        const int j = wv * 16 + nn;
        koff = (j >> 5) * 512 + ((j >> 3) & 3) * 128 + (j & 7) + q * 32;
        __syncthreads();
    }
    f32x4 hp = {0.f, 0.f, 0.f, 0.f};

    cg::grid_group grid = cg::this_grid();

    // ---- pre-phase: ALL blocks produce chunk 0 into buffer 0 ----
    {
        const int NT = spc * 4;
        for (int rt = bid; rt < NT; rt += gridDim.x)
            prod_tile(x, xg, plane, 0, rt, wv, lane, nn, q, wp, bb);
    }
    grid.sync();

    const int bbase = bid * 16;
    for (int c = 0; c < nc; ++c) {
        if (!cons) {
            if (c + 1 < nc) {     // produce chunk c+1 into the other buffer
                short* dst = xg + (size_t)((c + 1) & 1) * bufsz;
                const int t0 = (c + 1) * spc;
                const int NT = spc * 4;
                for (int rt = bid - 4; rt < NT; rt += gridDim.x - 4)
                    prod_tile(x, dst, plane, t0, rt, wv, lane, nn, q, wp, bb);
            }
        } else {
            const short* xgp = xg + (size_t)(c & 1) * bufsz
                             + ((size_t)(bid * 16 + wv) * 64 + lane) * 4;
            for (int tl = 0; tl < spc; ++tl) {
                const int gt = c * spc + tl;

                int2 gx = *(const int2*)(xgp);
                int2 gz = *(const int2*)(xgp + plane);
                int2 gn = *(const int2*)(xgp + 2 * plane);
                xgp += 16384;

                // out flush once per 32 steps (slots >=1 barrier old)
                if ((gt & 31) == 1 && gt >= 33 && tid < 512) {
                    const int s0 = gt - 33;
                    out[(size_t)(s0 + (tid >> 4)) * NB + bbase + (tid & 15)] =
                        oring[(((s0 >> 5) & 1) << 9) + (tid >> 4) * 16 + (tid & 15)];
                }

                const bool isfc = (gt > 0) && (wv == (gt & 15));
                f32x4 ar = {0.f,0.f,0.f,0.f}, az = {0.f,0.f,0.f,0.f};
                f32x4 an = {0.f,0.f,0.f,0.f}, afc = {0.f,0.f,0.f,0.f};
                const short* ab = abuf + (gt & 1) * 4096;
                #pragma unroll
                for (int cc = 0; cc < 8; ++cc) {
                    bf16x8 av = *(const bf16x8*)(ab + cc * 512 + lane * 8);
                    ar = mfma16(av, wr[cc], ar);
                    az = mfma16(av, wz[cc], az);
                    bf16x8 wnf = *(const bf16x8*)(wlds + (wv * 8 + cc) * 512 + lane * 8);
                    an = mfma16(av, wnf, an);
                    if (isfc)
                        afc = mfma16(av, *(const bf16x8*)(fcwl + cc * 512 + lane * 8), afc);
                }
                if (isfc && nn == 0) {
                    const int s = gt - 1;
                    f32x4 v;
                    #pragma unroll
                    for (int m = 0; m < 4; ++m) v[m] = afc[m] + fcb;
                    *(f32x4*)(oring + (((s >> 5) & 1) << 9) + ((s & 31) << 4) + q * 4) = v;
                }

                const float xr4[4] = { bflo(gx.x), bfhi(gx.x), bflo(gx.y), bfhi(gx.y) };
                const float xz4[4] = { bflo(gz.x), bfhi(gz.x), bflo(gz.y), bfhi(gz.y) };
                const float xn4[4] = { bflo(gn.x), bfhi(gn.x), bflo(gn.y), bfhi(gn.y) };

                short* hw = abuf + ((gt & 1) ^ 1) * 4096 + koff;
                #pragma unroll
                for (int m = 0; m < 4; ++m) {
                    float r_ = sigm(ar[m] + xr4[m]);
                    float z_ = sigm(az[m] + xz4[m]);
                    float n_ = tanh_(fmaf(r_, an[m] + bhn, xn4[m]));
                    float h_ = n_ + z_ * (hp[m] - n_);
                    hp[m] = h_;
                    hw[m * 8] = (short)f2bf(h_);
                }
                __syncthreads();   // single per-step barrier
            }
        }
        grid.sync();               // chunk boundary: xg buffers exchange
    }

    // ---- consumer tail: FC for step SEQ-1 (final h in buf 0), last flush --
    if (cons) {
        if (wv == 0) {
            f32x4 afc = {0.f, 0.f, 0.f, 0.f};
            #pragma unroll
            for (int cc = 0; cc < 8; ++cc)
                afc = mfma16(*(const bf16x8*)(abuf + cc * 512 + lane * 8),
                             *(const bf16x8*)(fcwl + cc * 512 + lane * 8), afc);
            if (nn == 0) {
                const int s = SEQ - 1;
                #pragma unroll
                for (int m = 0; m < 4; ++m)
                    oring[(((s >> 5) & 1) << 9) + ((s & 31) << 4) + q * 4 + m] = afc[m] + fcb;
            }
        }
        __syncthreads();
        if (tid < 512) {
            const int s0 = SEQ - 32;
            out[(size_t)(s0 + (tid >> 4)) * NB + bbase + (tid & 15)] =
                oring[(((s0 >> 5) & 1) << 9) + (tid >> 4) * 16 + (tid & 15)];
        }
    }
}

extern "C" void kernel_launch(void* const* d_in, const int* in_sizes, int n_in,
                              void* d_out, int out_size, void* d_ws, size_t ws_size,
                              hipStream_t stream) {
    (void)in_sizes; (void)n_in; (void)out_size;
    const float* x    = (const float*)d_in[0];
    const float* w_ih = (const float*)d_in[1];
    const float* w_hh = (const float*)d_in[2];
    const float* b_ih = (const float*)d_in[3];
    const float* b_hh = (const float*)d_in[4];
    const float* fc_w = (const float*)d_in[5];
    const float* fc_b = (const float*)d_in[6];
    float* out = (float*)d_out;
    short* xg  = (short*)d_ws;

    // largest chunk whose double buffer fits d_ws (98304 B per step)
    int spc = 64;
    for (int cand = 512; cand >= 64; cand >>= 1)
        if (2ull * cand * 98304ull <= ws_size) { spc = cand; break; }
    int nc = SEQ / spc;

    void* args[] = { (void*)&x, (void*)&w_ih, (void*)&w_hh, (void*)&b_ih,
                     (void*)&b_hh, (void*)&fc_w, (void*)&fc_b, (void*)&out,
                     (void*)&xg, (void*)&spc, (void*)&nc };
    hipLaunchCooperativeKernel((const void*)gru_coop, dim3(256), dim3(1024),
                               args, 0, stream);
}